// Round 4
// baseline (354.218 us; speedup 1.0000x reference)
//
#include <hip/hip_runtime.h>

typedef unsigned short u16;
typedef __bf16 bf16x8 __attribute__((ext_vector_type(8)));
typedef float f32x4 __attribute__((ext_vector_type(4)));

#define MFMA16(a,b,c) __builtin_amdgcn_mfma_f32_16x16x32_bf16(a,b,c,0,0,0)

static __device__ __forceinline__ u16 f2bf(float f){
  unsigned u = __builtin_bit_cast(unsigned, f);
  u += 0x7fffu + ((u>>16)&1u);
  return (u16)(u>>16);
}
static __device__ __forceinline__ int swz256(int r,int c){ return r*256 + (c ^ ((r&7)<<4)); }
static __device__ __forceinline__ int swz128(int r,int c){ return r*128 + (c ^ ((r&7)<<4)); }

// async global->LDS, 16B per lane; lds dest = wave-uniform base + lane*16
static __device__ __forceinline__ void gload16(const void* g, void* l){
  __builtin_amdgcn_global_load_lds(
      (const __attribute__((address_space(1))) unsigned int*)g,
      (__attribute__((address_space(3))) unsigned int*)l, 16, 0, 0);
}

// ---------------- fp32 -> bf16 convert ----------------
__global__ void conv_f2b(const float* __restrict__ in, u16* __restrict__ out, int n4){
  int i = blockIdx.x*256 + threadIdx.x;
  if (i >= n4) return;
  float4 f = reinterpret_cast<const float4*>(in)[i];
  ushort4 o; o.x=f2bf(f.x); o.y=f2bf(f.y); o.z=f2bf(f.z); o.w=f2bf(f.w);
  reinterpret_cast<ushort4*>(out)[i] = o;
}

// ---------------- float_mask -> bitmask (1 bit per element) ----------------
// out layout: [b][1024 q][128 bytes]; byte j covers k = j*8..j*8+7, bit i = k j*8+i
__global__ void mask2bits(const float* __restrict__ fm, unsigned char* __restrict__ bits){
  int i = blockIdx.x*256 + threadIdx.x;       // 1M bytes
  const float4* p = reinterpret_cast<const float4*>(fm + (size_t)i*8);
  float4 a = p[0], bq = p[1];
  unsigned v = 0;
  v |= (a.x  > 0.5f) ? 1u   : 0u;
  v |= (a.y  > 0.5f) ? 2u   : 0u;
  v |= (a.z  > 0.5f) ? 4u   : 0u;
  v |= (a.w  > 0.5f) ? 8u   : 0u;
  v |= (bq.x > 0.5f) ? 16u  : 0u;
  v |= (bq.y > 0.5f) ? 32u  : 0u;
  v |= (bq.z > 0.5f) ? 64u  : 0u;
  v |= (bq.w > 0.5f) ? 128u : 0u;
  bits[i] = (unsigned char)v;
}

// ---------------- bf16 NT GEMM: C[m][n] = sum_k A[m][k]*B[n][k] + bias[n] ----------------
template<int MODE>
__global__ __launch_bounds__(256) void gemm_nt(const u16* __restrict__ A, const u16* __restrict__ Bw,
    const float* __restrict__ bias, const float* __restrict__ resid,
    u16* __restrict__ Cb, float* __restrict__ Cf, int M, int N, int K)
{
  __shared__ uint4 ldsv[2048];               // 32 KB
  char* la = (char*)ldsv;
  char* lb = la + 16384;
  const int tid = threadIdx.x, lane = tid&63, w = tid>>6;
  const int l15 = lane&15, l4 = lane>>4;
  const int wm = w&1, wn = w>>1;
  const int mb = blockIdx.x, nb = blockIdx.y;
  const f32x4 zero4 = {0.f,0.f,0.f,0.f};
  f32x4 acc[4][4];
  #pragma unroll
  for (int i=0;i<4;++i)
    #pragma unroll
    for (int j=0;j<4;++j) acc[i][j] = zero4;

  for (int k0=0;k0<K;k0+=64){
    __syncthreads();
    #pragma unroll
    for (int it=0; it<4; ++it){
      int slot = it*256 + tid;
      int r = slot>>3, cg = (slot&7) ^ (r&7);
      gload16(A + (size_t)(mb*128+r)*K + k0 + cg*8, la + (it*256 + w*64)*16);
      gload16(Bw + (size_t)(nb*128+r)*K + k0 + cg*8, lb + (it*256 + w*64)*16);
    }
    __syncthreads();
    #pragma unroll
    for (int kk=0;kk<2;++kk){
      bf16x8 af[4], bfr[4];
      #pragma unroll
      for (int i=0;i<4;++i){
        af[i]  = *reinterpret_cast<const bf16x8*>(la + swz128(wm*64+i*16+l15, (kk*32+l4*8)*2));
        bfr[i] = *reinterpret_cast<const bf16x8*>(lb + swz128(wn*64+i*16+l15, (kk*32+l4*8)*2));
      }
      #pragma unroll
      for (int i=0;i<4;++i)
        #pragma unroll
        for (int j=0;j<4;++j)
          acc[i][j] = MFMA16(af[i], bfr[j], acc[i][j]);
    }
  }
  #pragma unroll
  for (int j=0;j<4;++j){
    int col = nb*128 + wn*64 + j*16 + l15;
    float bv = bias[col];
    #pragma unroll
    for (int i=0;i<4;++i){
      int row0 = mb*128 + wm*64 + i*16 + l4*4;
      if (MODE == 0){
        #pragma unroll
        for (int r=0;r<4;++r)
          Cb[(size_t)(row0+r)*N + col] = f2bf(acc[i][j][r] + bv);
      } else if (MODE == 1){
        int bb = row0 >> 10, kp = row0 & 1023;
        ushort4 o;
        o.x = f2bf(acc[i][j][0]+bv); o.y = f2bf(acc[i][j][1]+bv);
        o.z = f2bf(acc[i][j][2]+bv); o.w = f2bf(acc[i][j][3]+bv);
        *reinterpret_cast<ushort4*>(Cb + (size_t)(bb*1024+col)*1024 + kp) = o;
      } else {
        #pragma unroll
        for (int r=0;r<4;++r){
          size_t off = (size_t)(row0+r)*N + col;
          Cf[off] = acc[i][j][r] + bv + resid[off];
        }
      }
    }
  }
}

// ---------------- fused attention: KVB=128, raw-barrier counted-vmcnt ----------------
// 1D grid 1024 (XCD-swizzled), block 256 (4 waves, 16 q-rows each).
// K staged kv-PERMUTED (slot s holds kv (s&15)*8+(s>>4)) so S col for (fj,l15) is
// kv = l15*8+fj -> each lane owns 8 CONSECUTIVE kv -> 2x float4 old/raw access.
// Mask comes from a bit-packed table (1 byte per (row, 8kv) = exactly one tile-column).
__global__ __launch_bounds__(256) void attn_fused(const u16* __restrict__ qh,
    const u16* __restrict__ kh, const u16* __restrict__ vt,
    const float* __restrict__ oldsc, const unsigned char* __restrict__ bits,
    float* __restrict__ raw, u16* __restrict__ ao)
{
  __shared__ uint4 ldsv[5120];    // 80 KB
  char* lk_ = (char*)ldsv;        // K tile: 128 slot-rows x 128 d (256B rows, swz256, kv-permuted)
  char* lv_ = lk_ + 32768;        // V^T tile: 128 d-rows x 128 kv (256B rows, swz256)
  char* lp_ = lk_ + 65536;        // P: 64 q-rows x 128 kv bf16 (256B rows, swz256), wave-private
  const int tid = threadIdx.x, lane = tid&63, w = tid>>6;
  const int l15 = lane&15, l4 = lane>>4;
  // XCD swizzle: give each XCD 128 consecutive slots = 8 whole (b,h) groups
  unsigned u = blockIdx.x;
  int slotid = (u & 7) * 128 + (u >> 3);
  const int qb = slotid & 15, bh = slotid >> 4;
  const int b = bh & 7, h = bh >> 3;
  const float invT = 0.088388347648318447f;   // 1/sqrt(128)
  const f32x4 zero4 = {0.f,0.f,0.f,0.f};

  const int qglob = qb*64 + w*16 + l4*4;
  const float* oldp = oldsc + ((size_t)(h*8+b)*1024 + qglob)*1024 + l15*8;
  float*       rawp = raw   + ((size_t)(h*8+b)*1024 + qglob)*1024 + l15*8;
  const unsigned char* bitp = bits + ((size_t)b*1024 + qglob)*128 + l15;
  const u16* khB = kh + (size_t)b*1024*1024 + h*128;
  const u16* vtB = vt + ((size_t)b*1024 + h*128)*1024;

  bf16x8 qf[4];
  {
    const u16* qp = qh + (size_t)(b*1024 + qb*64 + w*16 + l15)*1024 + h*128 + l4*8;
    #pragma unroll
    for (int kk=0;kk<4;++kk)
      qf[kk] = __builtin_bit_cast(bf16x8, *reinterpret_cast<const uint4*>(qp + kk*32));
  }
  f32x4 oacc[8];
  #pragma unroll
  for (int i=0;i<8;++i) oacc[i] = zero4;
  float mr[4], lr[4];
  #pragma unroll
  for (int r=0;r<4;++r){ mr[r] = -3.0e38f; lr[r] = 0.f; }

  auto stage = [&](int kt){
    #pragma unroll
    for (int it=0; it<8; ++it){
      int slot = it*256 + tid;
      int rs = slot>>4, cs = slot&15;
      int ck = cs ^ (rs&7);
      int ks = (rs&15)*8 + (rs>>4);          // kv-permute
      gload16(khB + (size_t)(kt*128 + ks)*1024 + ck*8, lk_ + (it*256 + w*64)*16);
    }
    #pragma unroll
    for (int it=0; it<8; ++it){
      int slot = it*256 + tid;
      int rs = slot>>4, cs = slot&15;
      int cv = cs ^ (rs&7);
      gload16(vtB + (size_t)rs*1024 + kt*128 + cv*8, lv_ + (it*256 + w*64)*16);
    }
  };
  auto pref = [&](int kt, float4 (&o8)[4][2], unsigned (&bb)[4]){
    #pragma unroll
    for (int r=0;r<4;++r){
      o8[r][0] = *reinterpret_cast<const float4*>(oldp + (size_t)r*1024 + kt*128);
      o8[r][1] = *reinterpret_cast<const float4*>(oldp + (size_t)r*1024 + kt*128 + 4);
      bb[r] = bitp[(size_t)r*128 + kt*16];
    }
  };
  auto body = [&](int kt, float4 (&o8)[4][2], unsigned (&bb)[4]){
    // S = Q K^T  (8 col-fragments x 4 k-chunks)
    f32x4 fs[8];
    #pragma unroll
    for (int fj=0;fj<8;++fj){
      f32x4 s = zero4;
      #pragma unroll
      for (int kk=0;kk<4;++kk){
        bf16x8 kf = *reinterpret_cast<const bf16x8*>(lk_ + swz256(fj*16+l15, (kk*32+l4*8)*2));
        s = MFMA16(qf[kk], kf, s);
      }
      fs[fj] = s;
    }
    // raw = S + old; score = (raw - 1e8*!bit) * invT; row-max
    float tm[4];
    #pragma unroll
    for (int r=0;r<4;++r){
      float4 r0, r1;
      r0.x = fs[0][r] + o8[r][0].x; r0.y = fs[1][r] + o8[r][0].y;
      r0.z = fs[2][r] + o8[r][0].z; r0.w = fs[3][r] + o8[r][0].w;
      r1.x = fs[4][r] + o8[r][1].x; r1.y = fs[5][r] + o8[r][1].y;
      r1.z = fs[6][r] + o8[r][1].z; r1.w = fs[7][r] + o8[r][1].w;
      float4* rp = reinterpret_cast<float4*>(rawp + (size_t)r*1024 + kt*128);
      rp[0] = r0; rp[1] = r1;
      unsigned bv = bb[r];
      fs[0][r] = (r0.x - ((bv&1u)  ? 0.f : 1.0e8f)) * invT;
      fs[1][r] = (r0.y - ((bv&2u)  ? 0.f : 1.0e8f)) * invT;
      fs[2][r] = (r0.z - ((bv&4u)  ? 0.f : 1.0e8f)) * invT;
      fs[3][r] = (r0.w - ((bv&8u)  ? 0.f : 1.0e8f)) * invT;
      fs[4][r] = (r1.x - ((bv&16u) ? 0.f : 1.0e8f)) * invT;
      fs[5][r] = (r1.y - ((bv&32u) ? 0.f : 1.0e8f)) * invT;
      fs[6][r] = (r1.z - ((bv&64u) ? 0.f : 1.0e8f)) * invT;
      fs[7][r] = (r1.w - ((bv&128u)? 0.f : 1.0e8f)) * invT;
      float m0 = fmaxf(fmaxf(fs[0][r],fs[1][r]), fmaxf(fs[2][r],fs[3][r]));
      float m1 = fmaxf(fmaxf(fs[4][r],fs[5][r]), fmaxf(fs[6][r],fs[7][r]));
      tm[r] = fmaxf(m0, m1);
    }
    #pragma unroll
    for (int o=1;o<16;o<<=1){
      #pragma unroll
      for (int r=0;r<4;++r) tm[r] = fmaxf(tm[r], __shfl_xor(tm[r], o));
    }
    #pragma unroll
    for (int r=0;r<4;++r){
      float mn  = fmaxf(mr[r], tm[r]);
      float esc = __expf(mr[r] - mn);
      mr[r] = mn;
      lr[r] *= esc;
      #pragma unroll
      for (int nf=0;nf<8;++nf) oacc[nf][r] *= esc;
      float p[8];
      float ls = 0.f;
      #pragma unroll
      for (int fj=0;fj<8;++fj){ p[fj] = __expf(fs[fj][r] - mn); ls += p[fj]; }
      lr[r] += ls;
      u16 pk[8];
      #pragma unroll
      for (int fj=0;fj<8;++fj) pk[fj] = f2bf(p[fj]);
      int prow = w*16 + l4*4 + r;
      *reinterpret_cast<uint4*>(lp_ + swz256(prow, l15*16)) =
          *reinterpret_cast<const uint4*>(pk);
    }
    // PV: A = P rows (q), B = V^T rows (d), kv contracted in 4 chunks of 32
    #pragma unroll
    for (int kkv=0;kkv<4;++kkv){
      bf16x8 pf = *reinterpret_cast<const bf16x8*>(lp_ + swz256(w*16+l15, (kkv*32+l4*8)*2));
      #pragma unroll
      for (int nf=0;nf<8;++nf){
        bf16x8 vf = *reinterpret_cast<const bf16x8*>(lv_ + swz256(nf*16+l15, (kkv*32+l4*8)*2));
        oacc[nf] = MFMA16(pf, vf, oacc[nf]);
      }
    }
  };

  float4 oA[4][2], oB[4][2];
  unsigned bA[4], bB[4];
  pref(0, oA, bA);
  #pragma unroll 1
  for (int kt=0; kt<8; kt+=2){
    // ---- tile kt (uses A, prefetch B for kt+1) ----
    __builtin_amdgcn_s_barrier();                 // buffer free from previous readers
    stage(kt);
    __builtin_amdgcn_sched_barrier(0);
    pref(kt+1, oB, bB);
    __builtin_amdgcn_sched_barrier(0);
    asm volatile("s_waitcnt vmcnt(12)" ::: "memory");   // 16 stage done; 12 pref in flight
    __builtin_amdgcn_sched_barrier(0);
    __builtin_amdgcn_s_barrier();                 // all waves' staging landed
    __builtin_amdgcn_sched_barrier(0);
    body(kt, oA, bA);
    // ---- tile kt+1 (uses B, prefetch A for kt+2) ----
    __builtin_amdgcn_s_barrier();
    stage(kt+1);
    __builtin_amdgcn_sched_barrier(0);
    pref(kt+2 < 8 ? kt+2 : 7, oA, bA);
    __builtin_amdgcn_sched_barrier(0);
    asm volatile("s_waitcnt vmcnt(12)" ::: "memory");
    __builtin_amdgcn_sched_barrier(0);
    __builtin_amdgcn_s_barrier();
    __builtin_amdgcn_sched_barrier(0);
    body(kt+1, oB, bB);
  }

  #pragma unroll
  for (int o=1;o<16;o<<=1){
    #pragma unroll
    for (int r=0;r<4;++r) lr[r] += __shfl_xor(lr[r], o);
  }
  #pragma unroll
  for (int nf=0;nf<8;++nf){
    int col = h*128 + nf*16 + l15;
    #pragma unroll
    for (int r=0;r<4;++r){
      size_t orow = (size_t)(b*1024 + qb*64 + w*16 + l4*4 + r);
      ao[orow*1024 + col] = f2bf(oacc[nf][r] * (1.0f/lr[r]));
    }
  }
}

// ---------------- LayerNorm (in-place, row=1024) ----------------
__global__ __launch_bounds__(256) void ln_k(float* __restrict__ io,
    const float* __restrict__ g, const float* __restrict__ bb)
{
  const int lane = threadIdx.x & 63, w = threadIdx.x >> 6;
  size_t row = (size_t)blockIdx.x*4 + w;
  float4* p = reinterpret_cast<float4*>(io + row*1024);
  float4 x[4];
  float s = 0.f, s2 = 0.f;
  #pragma unroll
  for (int i=0;i<4;++i){
    x[i] = p[lane + i*64];
    s  += x[i].x + x[i].y + x[i].z + x[i].w;
    s2 += x[i].x*x[i].x + x[i].y*x[i].y + x[i].z*x[i].z + x[i].w*x[i].w;
  }
  #pragma unroll
  for (int o=1;o<64;o<<=1){ s += __shfl_xor(s,o); s2 += __shfl_xor(s2,o); }
  float mean = s * 0.0009765625f;
  float var  = s2 * 0.0009765625f - mean*mean;
  float rstd = rsqrtf(var + 1e-5f);
  const float4* gp = reinterpret_cast<const float4*>(g);
  const float4* bp = reinterpret_cast<const float4*>(bb);
  #pragma unroll
  for (int i=0;i<4;++i){
    float4 gg = gp[lane+i*64], bv = bp[lane+i*64], y;
    y.x = (x[i].x-mean)*rstd*gg.x + bv.x;
    y.y = (x[i].y-mean)*rstd*gg.y + bv.y;
    y.z = (x[i].z-mean)*rstd*gg.z + bv.z;
    y.w = (x[i].w-mean)*rstd*gg.w + bv.w;
    p[lane+i*64] = y;
  }
}

extern "C" void kernel_launch(void* const* d_in, const int* in_sizes, int n_in,
                              void* d_out, int out_size, void* d_ws, size_t ws_size,
                              hipStream_t stream)
{
  const float* q    = (const float*)d_in[0];
  const float* k    = (const float*)d_in[1];
  const float* v    = (const float*)d_in[2];
  const float* olds = (const float*)d_in[3];
  const float* fm   = (const float*)d_in[4];
  const float* wq   = (const float*)d_in[5];
  const float* bq   = (const float*)d_in[6];
  const float* wk   = (const float*)d_in[7];
  const float* bk   = (const float*)d_in[8];
  const float* wv   = (const float*)d_in[9];
  const float* bv   = (const float*)d_in[10];
  const float* wfc  = (const float*)d_in[11];
  const float* bfc  = (const float*)d_in[12];
  const float* lng  = (const float*)d_in[13];
  const float* lnb  = (const float*)d_in[14];
  float* out = (float*)d_out;
  float* raw = out + 8388608;          // 8*1024*1024 fp32 "out", then 64M fp32 "raw"

  u16* ws  = (u16*)d_ws;
  u16* qbf = ws;                        // 8192x512
  u16* kbf = qbf + 4194304;             // 8192x512
  u16* vbf = kbf + 4194304;             // 8192x1024
  u16* wqb = vbf + 8388608;             // 1024x512
  u16* wkb = wqb + 524288;
  u16* wvb = wkb + 524288;              // 1024x1024
  u16* wfb = wvb + 1048576;
  u16* qhb = wfb + 1048576;             // 8192x1024
  u16* khb = qhb + 8388608;
  u16* vtb = khb + 8388608;             // [b][h*128+d][1024]
  u16* aob = vtb + 8388608;             // 8192x1024
  unsigned char* bits = (unsigned char*)(aob + 8388608);   // 8*1024*128 = 1MB

  conv_f2b<<<4096,256,0,stream>>>(q,   qbf, 1048576);
  conv_f2b<<<4096,256,0,stream>>>(k,   kbf, 1048576);
  conv_f2b<<<8192,256,0,stream>>>(v,   vbf, 2097152);
  conv_f2b<<<512, 256,0,stream>>>(wq,  wqb, 131072);
  conv_f2b<<<512, 256,0,stream>>>(wk,  wkb, 131072);
  conv_f2b<<<1024,256,0,stream>>>(wv,  wvb, 262144);
  conv_f2b<<<1024,256,0,stream>>>(wfc, wfb, 262144);
  mask2bits<<<4096,256,0,stream>>>(fm, bits);

  gemm_nt<0><<<dim3(64,8),256,0,stream>>>(qbf, wqb, bq, nullptr, qhb, nullptr, 8192,1024,512);
  gemm_nt<0><<<dim3(64,8),256,0,stream>>>(kbf, wkb, bk, nullptr, khb, nullptr, 8192,1024,512);
  gemm_nt<1><<<dim3(64,8),256,0,stream>>>(vbf, wvb, bv, nullptr, vtb, nullptr, 8192,1024,1024);

  attn_fused<<<1024,256,0,stream>>>(qhb, khb, vtb, olds, bits, raw, aob);

  gemm_nt<2><<<dim3(64,8),256,0,stream>>>(aob, wfb, bfc, v, nullptr, out, 8192,1024,1024);
  ln_k<<<2048,256,0,stream>>>(out, lng, lnb);
}

// Round 5
// 303.424 us; speedup vs baseline: 1.1674x; 1.1674x over previous
//
#include <hip/hip_runtime.h>

typedef unsigned short u16;
typedef __bf16 bf16x8 __attribute__((ext_vector_type(8)));
typedef float f32x4 __attribute__((ext_vector_type(4)));

#define MFMA16(a,b,c) __builtin_amdgcn_mfma_f32_16x16x32_bf16(a,b,c,0,0,0)
#define WAITV(n) asm volatile("s_waitcnt vmcnt(" #n ")" ::: "memory")
#define SBAR()   __builtin_amdgcn_s_barrier()
#define SCHED0() __builtin_amdgcn_sched_barrier(0)

static __device__ __forceinline__ u16 f2bf(float f){
  unsigned u = __builtin_bit_cast(unsigned, f);
  u += 0x7fffu + ((u>>16)&1u);
  return (u16)(u>>16);
}
static __device__ __forceinline__ int swz256(int r,int c){ return r*256 + (c ^ ((r&7)<<4)); }
static __device__ __forceinline__ int swz128(int r,int c){ return r*128 + (c ^ ((r&7)<<4)); }

// async global->LDS, 16B per lane; lds dest = wave-uniform base + lane*16
static __device__ __forceinline__ void gload16(const void* g, void* l){
  __builtin_amdgcn_global_load_lds(
      (const __attribute__((address_space(1))) unsigned int*)g,
      (__attribute__((address_space(3))) unsigned int*)l, 16, 0, 0);
}

// ---------------- fp32 -> bf16 convert ----------------
__global__ void conv_f2b(const float* __restrict__ in, u16* __restrict__ out, int n4){
  int i = blockIdx.x*256 + threadIdx.x;
  if (i >= n4) return;
  float4 f = reinterpret_cast<const float4*>(in)[i];
  ushort4 o; o.x=f2bf(f.x); o.y=f2bf(f.y); o.z=f2bf(f.z); o.w=f2bf(f.w);
  reinterpret_cast<ushort4*>(out)[i] = o;
}

// ---------------- float_mask -> bitmask (1 bit per element) ----------------
__global__ void mask2bits(const float* __restrict__ fm, unsigned char* __restrict__ bits){
  int i = blockIdx.x*256 + threadIdx.x;       // 1M bytes
  const float4* p = reinterpret_cast<const float4*>(fm + (size_t)i*8);
  float4 a = p[0], bq = p[1];
  unsigned v = 0;
  v |= (a.x  > 0.5f) ? 1u   : 0u;
  v |= (a.y  > 0.5f) ? 2u   : 0u;
  v |= (a.z  > 0.5f) ? 4u   : 0u;
  v |= (a.w  > 0.5f) ? 8u   : 0u;
  v |= (bq.x > 0.5f) ? 16u  : 0u;
  v |= (bq.y > 0.5f) ? 32u  : 0u;
  v |= (bq.z > 0.5f) ? 64u  : 0u;
  v |= (bq.w > 0.5f) ? 128u : 0u;
  bits[i] = (unsigned char)v;
}

// ---------------- bf16 NT GEMM: C[m][n] = sum_k A[m][k]*B[n][k] + bias[n] ----------------
template<int MODE>
__global__ __launch_bounds__(256) void gemm_nt(const u16* __restrict__ A, const u16* __restrict__ Bw,
    const float* __restrict__ bias, const float* __restrict__ resid,
    u16* __restrict__ Cb, float* __restrict__ Cf, int M, int N, int K)
{
  __shared__ uint4 ldsv[2048];               // 32 KB
  char* la = (char*)ldsv;
  char* lb = la + 16384;
  const int tid = threadIdx.x, lane = tid&63, w = tid>>6;
  const int l15 = lane&15, l4 = lane>>4;
  const int wm = w&1, wn = w>>1;
  const int mb = blockIdx.x, nb = blockIdx.y;
  const f32x4 zero4 = {0.f,0.f,0.f,0.f};
  f32x4 acc[4][4];
  #pragma unroll
  for (int i=0;i<4;++i)
    #pragma unroll
    for (int j=0;j<4;++j) acc[i][j] = zero4;

  for (int k0=0;k0<K;k0+=64){
    __syncthreads();
    #pragma unroll
    for (int it=0; it<4; ++it){
      int slot = it*256 + tid;
      int r = slot>>3, cg = (slot&7) ^ (r&7);
      gload16(A + (size_t)(mb*128+r)*K + k0 + cg*8, la + (it*256 + w*64)*16);
      gload16(Bw + (size_t)(nb*128+r)*K + k0 + cg*8, lb + (it*256 + w*64)*16);
    }
    __syncthreads();
    #pragma unroll
    for (int kk=0;kk<2;++kk){
      bf16x8 af[4], bfr[4];
      #pragma unroll
      for (int i=0;i<4;++i){
        af[i]  = *reinterpret_cast<const bf16x8*>(la + swz128(wm*64+i*16+l15, (kk*32+l4*8)*2));
        bfr[i] = *reinterpret_cast<const bf16x8*>(lb + swz128(wn*64+i*16+l15, (kk*32+l4*8)*2));
      }
      #pragma unroll
      for (int i=0;i<4;++i)
        #pragma unroll
        for (int j=0;j<4;++j)
          acc[i][j] = MFMA16(af[i], bfr[j], acc[i][j]);
    }
  }
  #pragma unroll
  for (int j=0;j<4;++j){
    int col = nb*128 + wn*64 + j*16 + l15;
    float bv = bias[col];
    #pragma unroll
    for (int i=0;i<4;++i){
      int row0 = mb*128 + wm*64 + i*16 + l4*4;
      if (MODE == 0){
        #pragma unroll
        for (int r=0;r<4;++r)
          Cb[(size_t)(row0+r)*N + col] = f2bf(acc[i][j][r] + bv);
      } else if (MODE == 1){
        int bb = row0 >> 10, kp = row0 & 1023;
        ushort4 o;
        o.x = f2bf(acc[i][j][0]+bv); o.y = f2bf(acc[i][j][1]+bv);
        o.z = f2bf(acc[i][j][2]+bv); o.w = f2bf(acc[i][j][3]+bv);
        *reinterpret_cast<ushort4*>(Cb + (size_t)(bb*1024+col)*1024 + kp) = o;
      } else {
        #pragma unroll
        for (int r=0;r<4;++r){
          size_t off = (size_t)(row0+r)*N + col;
          Cf[off] = acc[i][j][r] + bv + resid[off];
        }
      }
    }
  }
}

// ---------------- fused attention: KVB=64, cross-barrier counted-vmcnt pipeline ----------
// 1D grid 1024 (XCD-swizzled), block 256 (4 waves, 16 q-rows each).
// K staged kv-PERMUTED (slot s holds kv (s&15)*4+(s>>4)) so S col for (fj,l15) is
// kv = l15*4+fj -> each lane owns 4 consecutive kv -> float4 old/raw access.
// Per tile t:  SBAR; stage(t+1 -> buf^1); vmcnt(16); SBAR; body(t); pref(t+2).
// Steady state: {pref(t+1), stage(t+1)} = 16 loads stay in flight across body(t).
__global__ __launch_bounds__(256) void attn_fused(const u16* __restrict__ qh,
    const u16* __restrict__ kh, const u16* __restrict__ vt,
    const float* __restrict__ oldsc, const unsigned char* __restrict__ bits,
    float* __restrict__ raw, u16* __restrict__ ao)
{
  __shared__ uint4 ldsv[4608];    // 72 KB
  char* lk0 = (char*)ldsv;        // K buf0: 64 x 128 bf16 (swz256, kv-permuted) 16KB
  char* lv0 = lk0 + 16384;        // V^T buf0: 128 x 64 bf16 (swz128) 16KB
  char* lk1 = lk0 + 32768;
  char* lv1 = lk0 + 49152;
  char* lp_ = lk0 + 65536;        // P: 64 x 64 bf16 (swz128), wave-private rows, 8KB
  const int tid = threadIdx.x, lane = tid&63, w = tid>>6;
  const int l15 = lane&15, l4 = lane>>4;
  unsigned ublk = blockIdx.x;
  int slotid = (ublk & 7) * 128 + (ublk >> 3);       // XCD-contiguous (b,h) groups
  const int qb = slotid & 15, bh = slotid >> 4;
  const int b = bh & 7, h = bh >> 3;
  const float invT = 0.088388347648318447f;   // 1/sqrt(128)
  const f32x4 zero4 = {0.f,0.f,0.f,0.f};

  const int qglob = qb*64 + w*16 + l4*4;
  const float* oldp = oldsc + ((size_t)(h*8+b)*1024 + qglob)*1024 + l15*4;
  float*       rawp = raw   + ((size_t)(h*8+b)*1024 + qglob)*1024 + l15*4;
  const unsigned char* bitp = bits + ((size_t)b*1024 + qglob)*128 + (l15>>1);
  const u16* khB = kh + (size_t)b*1024*1024 + h*128;
  const u16* vtB = vt + ((size_t)b*1024 + h*128)*1024;
  const int nsh = (l15&1)*4;      // nibble shift for this lane's 4 kv bits

  bf16x8 qf[4];
  {
    const u16* qp = qh + (size_t)(b*1024 + qb*64 + w*16 + l15)*1024 + h*128 + l4*8;
    #pragma unroll
    for (int kk=0;kk<4;++kk)
      qf[kk] = __builtin_bit_cast(bf16x8, *reinterpret_cast<const uint4*>(qp + kk*32));
  }
  f32x4 oacc[8];
  #pragma unroll
  for (int i=0;i<8;++i) oacc[i] = zero4;
  float mr[4], lr[4];
  #pragma unroll
  for (int r=0;r<4;++r){ mr[r] = -3.0e38f; lr[r] = 0.f; }

  auto stage = [&](int kt, char* lkD, char* lvD){
    #pragma unroll
    for (int it=0; it<4; ++it){
      int slot = it*256 + tid;
      int rs = slot>>4, cs = slot&15;
      int ck = cs ^ (rs&7);
      int kv = (rs&15)*4 + (rs>>4);
      gload16(khB + (size_t)(kt*64 + kv)*1024 + ck*8, lkD + (it*256 + w*64)*16);
      int r8 = slot>>3, cgv = (slot&7) ^ (r8&7);
      gload16(vtB + (size_t)r8*1024 + kt*64 + cgv*8, lvD + (it*256 + w*64)*16);
    }
  };
  auto pref = [&](int kt, float4 (&o4)[4], unsigned char (&bb)[4]){
    #pragma unroll
    for (int r=0;r<4;++r){
      o4[r] = *reinterpret_cast<const float4*>(oldp + (size_t)r*1024 + kt*64);
      bb[r] = bitp[(size_t)r*128 + kt*8];
    }
  };
  auto body = [&](int kt, char* lkR, char* lvR, float4 (&o4)[4], unsigned char (&bb)[4]){
    f32x4 fs[4];
    #pragma unroll
    for (int fj=0;fj<4;++fj){
      f32x4 s = zero4;
      #pragma unroll
      for (int kk=0;kk<4;++kk){
        bf16x8 kf = *reinterpret_cast<const bf16x8*>(lkR + swz256(fj*16+l15, (kk*32+l4*8)*2));
        s = MFMA16(qf[kk], kf, s);
      }
      fs[fj] = s;
    }
    float tm[4];
    #pragma unroll
    for (int r=0;r<4;++r){
      float4 rv;
      rv.x = fs[0][r] + o4[r].x; rv.y = fs[1][r] + o4[r].y;
      rv.z = fs[2][r] + o4[r].z; rv.w = fs[3][r] + o4[r].w;
      *reinterpret_cast<float4*>(rawp + (size_t)r*1024 + kt*64) = rv;
      unsigned nib = ((unsigned)bb[r]) >> nsh;
      fs[0][r] = (rv.x - ((nib&1u) ? 0.f : 1.0e8f)) * invT;
      fs[1][r] = (rv.y - ((nib&2u) ? 0.f : 1.0e8f)) * invT;
      fs[2][r] = (rv.z - ((nib&4u) ? 0.f : 1.0e8f)) * invT;
      fs[3][r] = (rv.w - ((nib&8u) ? 0.f : 1.0e8f)) * invT;
      tm[r] = fmaxf(fmaxf(fs[0][r], fs[1][r]), fmaxf(fs[2][r], fs[3][r]));
    }
    #pragma unroll
    for (int o=1;o<16;o<<=1){
      #pragma unroll
      for (int r=0;r<4;++r) tm[r] = fmaxf(tm[r], __shfl_xor(tm[r], o));
    }
    #pragma unroll
    for (int r=0;r<4;++r){
      float mn  = fmaxf(mr[r], tm[r]);
      float esc = __expf(mr[r] - mn);
      mr[r] = mn;
      lr[r] *= esc;
      #pragma unroll
      for (int nf=0;nf<8;++nf) oacc[nf][r] *= esc;
      float px = __expf(fs[0][r] - mn), py = __expf(fs[1][r] - mn);
      float pz = __expf(fs[2][r] - mn), pw = __expf(fs[3][r] - mn);
      lr[r] += px + py + pz + pw;
      ushort4 o;
      o.x = f2bf(px); o.y = f2bf(py); o.z = f2bf(pz); o.w = f2bf(pw);
      int prow = w*16 + l4*4 + r;
      *reinterpret_cast<ushort4*>(lp_ + swz128(prow, l15*8)) = o;
    }
    #pragma unroll
    for (int kkv=0;kkv<2;++kkv){
      bf16x8 pf = *reinterpret_cast<const bf16x8*>(lp_ + swz128(w*16+l15, (kkv*32+l4*8)*2));
      #pragma unroll
      for (int nf=0;nf<8;++nf){
        bf16x8 vf = *reinterpret_cast<const bf16x8*>(lvR + swz128(nf*16+l15, (kkv*32+l4*8)*2));
        oacc[nf] = MFMA16(pf, vf, oacc[nf]);
      }
    }
  };

  float4 oA[4], oB[4];
  unsigned char bA[4], bB[4];
  // prologue: establish {pref(t+1)} in flight, tiles 0,1 staged
  stage(0, lk0, lv0);          // 8
  stage(1, lk1, lv1);          // 8
  pref(0, oA, bA);             // 8
  pref(1, oB, bB);             // 8  -> 32 outstanding
  WAITV(8);                    // completes s0,s1,p0; leaves p1
  SBAR(); SCHED0();
  body(0, lk0, lv0, oA, bA);
  pref(2, oA, bA);             // -> p1,p2 = 16 in flight

  #pragma unroll 1
  for (int t = 1; t <= 13; t += 2){
    // ---- odd t: reads buf1 + oB; stages t+1 -> buf0 ----
    SBAR();                         // all waves done reading buf0 (body t-1)
    stage(t+1, lk0, lv0);           // -> 24
    WAITV(16);                      // completes pref(t) [+ stage(t), done earlier]
    SBAR(); SCHED0();
    body(t, lk1, lv1, oB, bB);
    if (t+2 <= 15) pref(t+2, oB, bB);
    // ---- even t+1: reads buf0 + oA; stages t+2 -> buf1 ----
    SBAR();
    stage(t+2, lk1, lv1);
    WAITV(16);                      // completes pref(t+1) + stage(t+1)
    SBAR(); SCHED0();
    body(t+1, lk0, lv0, oA, bA);
    if (t+3 <= 15) pref(t+3, oA, bA);
  }
  // t = 15 (odd, buf1, oB): nothing left to stage/pref
  SBAR();
  WAITV(0);
  SBAR(); SCHED0();
  body(15, lk1, lv1, oB, bB);

  #pragma unroll
  for (int o=1;o<16;o<<=1){
    #pragma unroll
    for (int r=0;r<4;++r) lr[r] += __shfl_xor(lr[r], o);
  }
  #pragma unroll
  for (int nf=0;nf<8;++nf){
    int col = h*128 + nf*16 + l15;
    #pragma unroll
    for (int r=0;r<4;++r){
      size_t orow = (size_t)(b*1024 + qb*64 + w*16 + l4*4 + r);
      ao[orow*1024 + col] = f2bf(oacc[nf][r] * (1.0f/lr[r]));
    }
  }
}

// ---------------- LayerNorm (in-place, row=1024) ----------------
__global__ __launch_bounds__(256) void ln_k(float* __restrict__ io,
    const float* __restrict__ g, const float* __restrict__ bb)
{
  const int lane = threadIdx.x & 63, w = threadIdx.x >> 6;
  size_t row = (size_t)blockIdx.x*4 + w;
  float4* p = reinterpret_cast<float4*>(io + row*1024);
  float4 x[4];
  float s = 0.f, s2 = 0.f;
  #pragma unroll
  for (int i=0;i<4;++i){
    x[i] = p[lane + i*64];
    s  += x[i].x + x[i].y + x[i].z + x[i].w;
    s2 += x[i].x*x[i].x + x[i].y*x[i].y + x[i].z*x[i].z + x[i].w*x[i].w;
  }
  #pragma unroll
  for (int o=1;o<64;o<<=1){ s += __shfl_xor(s,o); s2 += __shfl_xor(s2,o); }
  float mean = s * 0.0009765625f;
  float var  = s2 * 0.0009765625f - mean*mean;
  float rstd = rsqrtf(var + 1e-5f);
  const float4* gp = reinterpret_cast<const float4*>(g);
  const float4* bp = reinterpret_cast<const float4*>(bb);
  #pragma unroll
  for (int i=0;i<4;++i){
    float4 gg = gp[lane+i*64], bv = bp[lane+i*64], y;
    y.x = (x[i].x-mean)*rstd*gg.x + bv.x;
    y.y = (x[i].y-mean)*rstd*gg.y + bv.y;
    y.z = (x[i].z-mean)*rstd*gg.z + bv.z;
    y.w = (x[i].w-mean)*rstd*gg.w + bv.w;
    p[lane+i*64] = y;
  }
}

extern "C" void kernel_launch(void* const* d_in, const int* in_sizes, int n_in,
                              void* d_out, int out_size, void* d_ws, size_t ws_size,
                              hipStream_t stream)
{
  const float* q    = (const float*)d_in[0];
  const float* k    = (const float*)d_in[1];
  const float* v    = (const float*)d_in[2];
  const float* olds = (const float*)d_in[3];
  const float* fm   = (const float*)d_in[4];
  const float* wq   = (const float*)d_in[5];
  const float* bq   = (const float*)d_in[6];
  const float* wk   = (const float*)d_in[7];
  const float* bk   = (const float*)d_in[8];
  const float* wv   = (const float*)d_in[9];
  const float* bv   = (const float*)d_in[10];
  const float* wfc  = (const float*)d_in[11];
  const float* bfc  = (const float*)d_in[12];
  const float* lng  = (const float*)d_in[13];
  const float* lnb  = (const float*)d_in[14];
  float* out = (float*)d_out;
  float* raw = out + 8388608;          // 8*1024*1024 fp32 "out", then 64M fp32 "raw"

  u16* ws  = (u16*)d_ws;
  u16* qbf = ws;                        // 8192x512
  u16* kbf = qbf + 4194304;             // 8192x512
  u16* vbf = kbf + 4194304;             // 8192x1024
  u16* wqb = vbf + 8388608;             // 1024x512
  u16* wkb = wqb + 524288;
  u16* wvb = wkb + 524288;              // 1024x1024
  u16* wfb = wvb + 1048576;
  u16* qhb = wfb + 1048576;             // 8192x1024
  u16* khb = qhb + 8388608;
  u16* vtb = khb + 8388608;             // [b][h*128+d][1024]
  u16* aob = vtb + 8388608;             // 8192x1024
  unsigned char* bits = (unsigned char*)(aob + 8388608);   // 8*1024*128 = 1MB

  conv_f2b<<<4096,256,0,stream>>>(q,   qbf, 1048576);
  conv_f2b<<<4096,256,0,stream>>>(k,   kbf, 1048576);
  conv_f2b<<<8192,256,0,stream>>>(v,   vbf, 2097152);
  conv_f2b<<<512, 256,0,stream>>>(wq,  wqb, 131072);
  conv_f2b<<<512, 256,0,stream>>>(wk,  wkb, 131072);
  conv_f2b<<<1024,256,0,stream>>>(wv,  wvb, 262144);
  conv_f2b<<<1024,256,0,stream>>>(wfc, wfb, 262144);
  mask2bits<<<4096,256,0,stream>>>(fm, bits);

  gemm_nt<0><<<dim3(64,8),256,0,stream>>>(qbf, wqb, bq, nullptr, qhb, nullptr, 8192,1024,512);
  gemm_nt<0><<<dim3(64,8),256,0,stream>>>(kbf, wkb, bk, nullptr, khb, nullptr, 8192,1024,512);
  gemm_nt<1><<<dim3(64,8),256,0,stream>>>(vbf, wvb, bv, nullptr, vtb, nullptr, 8192,1024,1024);

  attn_fused<<<1024,256,0,stream>>>(qhb, khb, vtb, olds, bits, raw, aob);

  gemm_nt<2><<<dim3(64,8),256,0,stream>>>(aob, wfb, bfc, v, nullptr, out, 8192,1024,1024);
  ln_k<<<2048,256,0,stream>>>(out, lng, lnb);
}